// Round 5
// baseline (92.294 us; speedup 1.0000x reference)
//
#include <hip/hip_runtime.h>

#define D    32       // feature dim (fixed)
#define BLK  256      // threads per block (4 waves, 64 i-rows per block)
#define BLKP 64       // precompute block (wide grid: latency-bound kernel)
#define NCH  16       // j-chunks per batch -> grid.y
#define SJ   128      // j-rows staged in LDS per stage (8 MFMA tiles)

#define LOG2E 1.44269504088896340736f

typedef short  short8  __attribute__((ext_vector_type(8)));
typedef float  floatx4 __attribute__((ext_vector_type(4)));
typedef float  v2f     __attribute__((ext_vector_type(2)));

__device__ __forceinline__ short f2bf(float v) {       // fp32 -> bf16 (RTNE-ish)
    union { float f; unsigned u; } x; x.f = v;
    unsigned r = x.u + 0x7fffu + ((x.u >> 16) & 1u);
    return (short)(r >> 16);
}
__device__ __forceinline__ float bf2f(short h) {
    union { float f; unsigned u; } x;
    x.u = ((unsigned)(unsigned short)h) << 16;
    return x.f;
}
__device__ __forceinline__ float fast_exp2(float x) {
#if __has_builtin(__builtin_amdgcn_exp2f)
    return __builtin_amdgcn_exp2f(x);
#else
    return exp2f(x);
#endif
}

// ---------------------------------------------------------------------------
// Kernel P: per-row precompute + zero-init + global bf16 hi/lo split of fea2
// stored FRAGMENT-MAJOR: for row n (tile t=n/16, m=n%16), k-octet q, the
// 8 bf16 go to slot l=m+16q of tile t:  gX[(t*64 + l)*8 .. +8).
// ---------------------------------------------------------------------------
__global__ __launch_bounds__(BLKP) void precompute_kernel(
    const float* __restrict__ points,
    const float* __restrict__ fea1,
    const float* __restrict__ fea2,
    float4* __restrict__ xp,
    float* __restrict__ f1n,
    float* __restrict__ f2n,
    short* __restrict__ f2hi,
    short* __restrict__ f2lo,
    float* __restrict__ acc,
    float* __restrict__ out,
    int BN, int Bsz)
{
    int r = blockIdx.x * BLKP + threadIdx.x;
    if (r < Bsz) out[r] = 0.0f;
    if (r >= BN) return;
#pragma unroll
    for (int s = 0; s < 5; ++s) acc[s * BN + r] = 0.0f;

    const float s20 = 20.0f;                 // 1/SIGMA
    float x = points[3*r+0] * s20;
    float y = points[3*r+1] * s20;
    float z = points[3*r+2] * s20;
    float4 v; v.x = x; v.y = y; v.z = z;
    v.w = (x*x + y*y + z*z) * LOG2E;
    xp[r] = v;

    // f1 norm
    const float4* p1 = (const float4*)(fea1 + (size_t)r * D);
    float n1 = 0.f;
#pragma unroll
    for (int k = 0; k < D/4; ++k) {
        float4 a = p1[k];
        n1 = fmaf(a.x,a.x, fmaf(a.y,a.y, fmaf(a.z,a.z, fmaf(a.w,a.w, n1))));
    }
    f1n[r] = n1 * LOG2E;

    // f2: norm + hi/lo split, scattered fragment-major
    const int t = r >> 4;                    // global 16-row tile id
    const int m = r & 15;
    const float* p2 = fea2 + (size_t)r * D;
    float n2 = 0.f;
#pragma unroll
    for (int q = 0; q < 4; ++q) {
        float4 v0 = *(const float4*)(p2 + q*8);
        float4 v1 = *(const float4*)(p2 + q*8 + 4);
        float e[8] = {v0.x,v0.y,v0.z,v0.w,v1.x,v1.y,v1.z,v1.w};
        short8 h, l;
#pragma unroll
        for (int k = 0; k < 8; ++k) {
            n2 = fmaf(e[k], e[k], n2);
            short hh = f2bf(e[k]);
            h[k] = hh;
            l[k] = f2bf(e[k] - bf2f(hh));
        }
        size_t off = ((size_t)t * 64 + m + 16*q) * 8;
        *(short8*)&f2hi[off] = h;
        *(short8*)&f2lo[off] = l;
    }
    f2n[r] = n2 * LOG2E;
}

// ---------------------------------------------------------------------------
// Kernel A: pair loop -- exact R4/baseline structure EXCEPT the per-pair
// j-scalars (xp[j], f2n[j]) are read from GLOBAL (L1-resident) instead of
// LDS; sXJ/sFN deleted.
//   Theory: per-CU LDS-pipe serialization was ~96cyc/tile (49K cyc = ~20us
//   of pair's ~30us); the 4x sXJ b128 + 4x sFN b32 broadcast reads are 72
//   of those cycles, 16-way redundant. Moving them to VMEM: 4 distinct 16B
//   lines/wave/instr, 5KB chunk working set shared by all ~8 co-resident
//   blocks (same blockIdx.y) -> L1 hits; VMEM pipe is near-idle (~3us).
//   LDS drops to frags-only (2x b128/tile) + staging writes (~6us/CU).
//   Registers: +~6 transients, still under the 64-VGPR cap (launch_bounds
//   (256,8) retained -> 8 waves/SIMD preserved). Reduce path untouched
//   (5x2 shuffles; shuffles are LDS-pipe, so we keep them minimal).
// ---------------------------------------------------------------------------
__global__ __launch_bounds__(BLK, 8) void pair_kernel(
    const float* __restrict__ fea1,
    const short* __restrict__ f2hi,
    const short* __restrict__ f2lo,
    const float4* __restrict__ xp,
    const float* __restrict__ f1n,
    const float* __restrict__ f2n,
    float* __restrict__ acc,
    int N, int BN)
{
    __shared__ __align__(16) short sHi[SJ * D];   // 8 KB, fragment-major
    __shared__ __align__(16) short sLo[SJ * D];   // 8 KB

    const int tid  = threadIdx.x;
    const int lane = tid & 63;
    const int wv   = tid >> 6;
    const int m    = lane & 15;        // i-offset (B n-index / C col)
    const int q    = lane >> 4;        // k-octet / j-quad

    const int ibpb  = N / 64;          // i-blocks per batch
    const int b     = blockIdx.x / ibpb;
    const int ibase = blockIdx.x * 64 + wv * 16;
    const int JCH   = N / NCH;
    const int jc0   = blockIdx.y * JCH;

    // ---- B fragments: f1 rows of this wave's 16 i's, split hi/lo ----
    const float* f1p = fea1 + (size_t)(ibase + m) * D + q * 8;
    float4 bv0 = *(const float4*)(f1p);
    float4 bv1 = *(const float4*)(f1p + 4);
    float bf[8] = {bv0.x,bv0.y,bv0.z,bv0.w,bv1.x,bv1.y,bv1.z,bv1.w};
    short8 Bhi, Blo;
#pragma unroll
    for (int k = 0; k < 8; ++k) {
        short h = f2bf(bf[k]);
        Bhi[k] = h;
        Blo[k] = f2bf(bf[k] - bf2f(h));
    }

    const float L2 = 2.0f * LOG2E;
    float4 xi = xp[ibase + m];
    float xix = xi.x * L2, xiy = xi.y * L2, xiz = xi.z * L2;
    float mxiw = -xi.w;
    float nfi  = -f1n[ibase + m];      // -log2e*|f1_i|^2

    v2f sAB = {0.f, 0.f};              // (sum e^a, sum e^b)
    v2f s2  = {0.f, 0.f};              // (sum e^2a, sum e^2b)
    float sab = 0.f;                   // sum e^a e^b

    const short*  gHi  = f2hi + ((size_t)(b * N + jc0) >> 4) * 512;
    const short*  gLo  = f2lo + ((size_t)(b * N + jc0) >> 4) * 512;
    const float4* xpb  = xp  + (size_t)b * N + jc0;
    const float*  f2nb = f2n + (size_t)b * N + jc0;

    for (int s = 0; s < JCH; s += SJ) {
        // ---- stage: pure contiguous copy (8 KB hi + 8 KB lo) ----
        const uint4* srcH = (const uint4*)(gHi + (size_t)(s >> 4) * 512);
        const uint4* srcL = (const uint4*)(gLo + (size_t)(s >> 4) * 512);
        uint4* dstH = (uint4*)sHi;
        uint4* dstL = (uint4*)sLo;
        dstH[tid]       = srcH[tid];
        dstH[tid + 256] = srcH[tid + 256];
        dstL[tid]       = srcL[tid];
        dstL[tid + 256] = srcL[tid + 256];
        __syncthreads();

        const float4* xps = xpb + s;   // this stage's j-scalars (global, L1)
        const float*  fns = f2nb + s;

        // ---- compute: 8 16x16 pair tiles ----
#pragma unroll 2
        for (int jt8 = 0; jt8 < SJ/16; ++jt8) {
            const short8 Ahi = *(const short8*)&sHi[(jt8 * 64 + lane) * 8];
            const short8 Alo = *(const short8*)&sLo[(jt8 * 64 + lane) * 8];
            floatx4 c = {0.f, 0.f, 0.f, 0.f};
            c = __builtin_amdgcn_mfma_f32_16x16x32_bf16(Ahi, Bhi, c, 0, 0, 0);
            c = __builtin_amdgcn_mfma_f32_16x16x32_bf16(Ahi, Blo, c, 0, 0, 0);
            c = __builtin_amdgcn_mfma_f32_16x16x32_bf16(Alo, Bhi, c, 0, 0, 0);
#pragma unroll
            for (int r = 0; r < 4; ++r) {
                int jl = jt8 * 16 + q * 4 + r;
                float4 xj = xps[jl];                            // global/L1
                float bL = fmaf(c[r], L2, nfi - fns[jl]);       // log2 feature
                float aL = fmaf(xiz, xj.z,
                             fmaf(xiy, xj.y,
                              fmaf(xix, xj.x, mxiw))) - xj.w;   // log2 spatial
                float ea = fast_exp2(aL);
                float eb = fast_exp2(bL);
                v2f e = {ea, eb};
                sAB += e;                                   // v_pk_add_f32
                s2   = __builtin_elementwise_fma(e, e, s2); // v_pk_fma_f32
                sab  = fmaf(ea, eb, sab);
            }
        }
        __syncthreads();
    }

    // ---- reduce the 4 j-quads (lanes sharing lane&15) ----
    float vA = sAB.x, vB = sAB.y, v2a = s2.x, v2b = s2.y, vab = sab;
    vA  += __shfl_xor(vA, 16);  vA  += __shfl_xor(vA, 32);
    vB  += __shfl_xor(vB, 16);  vB  += __shfl_xor(vB, 32);
    v2a += __shfl_xor(v2a, 16); v2a += __shfl_xor(v2a, 32);
    v2b += __shfl_xor(v2b, 16); v2b += __shfl_xor(v2b, 32);
    vab += __shfl_xor(vab, 16); vab += __shfl_xor(vab, 32);

    if (lane < 16) {
        int row = ibase + lane;
        atomicAdd(&acc[0*BN + row], vA);
        atomicAdd(&acc[1*BN + row], v2a);
        atomicAdd(&acc[2*BN + row], vB);
        atomicAdd(&acc[3*BN + row], v2b);
        atomicAdd(&acc[4*BN + row], vab);
    }
}

// ---------------------------------------------------------------------------
// Kernel B: combine per-row sums, weight, reduce into out[b] (out zeroed by P).
//   out[b] = sum_i w_i * ( S2a/A^2 - 2*Sab/(A*B) + S2b/B^2 )
// ---------------------------------------------------------------------------
__global__ __launch_bounds__(BLK) void finalize_kernel(
    const float* __restrict__ acc,
    const float* __restrict__ weights,
    float* __restrict__ out,
    int N, int BN)
{
    int row = blockIdx.x * BLK + threadIdx.x;
    int b   = (blockIdx.x * BLK) / N;

    float A   = acc[0*BN + row];
    float S2a = acc[1*BN + row];
    float Bt  = acc[2*BN + row];
    float S2b = acc[3*BN + row];
    float Sab = acc[4*BN + row];
    float invA = 1.0f / A;
    float invB = 1.0f / Bt;
    float val  = S2a*invA*invA - 2.0f*Sab*invA*invB + S2b*invB*invB;
    float sum  = weights[row] * val;

    __shared__ float red[BLK/64];
    for (int off = 32; off > 0; off >>= 1)
        sum += __shfl_down(sum, off);
    if ((threadIdx.x & 63) == 0) red[threadIdx.x >> 6] = sum;
    __syncthreads();
    if (threadIdx.x == 0) {
        float s = 0.f;
#pragma unroll
        for (int w = 0; w < BLK/64; ++w) s += red[w];
        atomicAdd(&out[b], s);
    }
}

// ---------------------------------------------------------------------------
extern "C" void kernel_launch(void* const* d_in, const int* in_sizes, int n_in,
                              void* d_out, int out_size, void* d_ws, size_t ws_size,
                              hipStream_t stream) {
    const float* points  = (const float*)d_in[0];
    const float* fea1    = (const float*)d_in[1];
    const float* fea2    = (const float*)d_in[2];
    const float* weights = (const float*)d_in[3];
    float* out = (float*)d_out;

    int B  = out_size;          // 2
    int BN = in_sizes[3];       // B*N = 8192
    int N  = BN / B;            // 4096

    // workspace (bytes):
    //   acc  : 5*BN*4   @ 0
    //   xp   : 4*BN*4   @ 5*BN*4
    //   f2n  : BN*4     @ 9*BN*4
    //   f1n  : BN*4     @ 10*BN*4
    //   f2hi : BN*D*2   @ 11*BN*4
    //   f2lo : BN*D*2
    float*  acc  = (float*)d_ws;
    float4* xp   = (float4*)((char*)d_ws + (size_t)5  * BN * 4);
    float*  f2n  = (float*)((char*)d_ws + (size_t)9  * BN * 4);
    float*  f1n  = (float*)((char*)d_ws + (size_t)10 * BN * 4);
    short*  f2hi = (short*)((char*)d_ws + (size_t)11 * BN * 4);
    short*  f2lo = f2hi + (size_t)BN * D;

    precompute_kernel<<<dim3((BN + BLKP - 1) / BLKP), dim3(BLKP), 0, stream>>>(
        points, fea1, fea2, xp, f1n, f2n, f2hi, f2lo, acc, out, BN, B);

    dim3 grid(BN / 64, NCH);    // 128 x 16 = 2048 blocks (8 blocks/CU)
    pair_kernel<<<grid, dim3(BLK), 0, stream>>>(
        fea1, f2hi, f2lo, xp, f1n, f2n, acc, N, BN);

    finalize_kernel<<<dim3(BN / BLK), dim3(BLK), 0, stream>>>(acc, weights, out, N, BN);
}

// Round 6
// 82.547 us; speedup vs baseline: 1.1181x; 1.1181x over previous
//
#include <hip/hip_runtime.h>

#define D    32       // feature dim (fixed)
#define BLK  256      // threads per block (4 waves, 64 i-rows per block)
#define BLKP 64       // precompute block (wide grid: latency-bound kernel)
#define NCH  16       // j-chunks per batch -> grid.y
#define SJ   128      // j-rows staged in LDS per stage (8 MFMA tiles)

#define LOG2E 1.44269504088896340736f

typedef short  short8  __attribute__((ext_vector_type(8)));
typedef float  floatx4 __attribute__((ext_vector_type(4)));
typedef float  v2f     __attribute__((ext_vector_type(2)));

__device__ __forceinline__ short f2bf(float v) {       // fp32 -> bf16 (RTNE-ish)
    union { float f; unsigned u; } x; x.f = v;
    unsigned r = x.u + 0x7fffu + ((x.u >> 16) & 1u);
    return (short)(r >> 16);
}
__device__ __forceinline__ float bf2f(short h) {
    union { float f; unsigned u; } x;
    x.u = ((unsigned)(unsigned short)h) << 16;
    return x.f;
}
__device__ __forceinline__ float fast_exp2(float x) {
#if __has_builtin(__builtin_amdgcn_exp2f)
    return __builtin_amdgcn_exp2f(x);
#else
    return exp2f(x);
#endif
}

// ---------------------------------------------------------------------------
// Kernel P: per-row precompute + zero-init + global bf16 hi/lo split of fea2
// (fragment-major, unchanged) + PAIRED-SoA j-scalar pack jpk:
//   per j-pair p (rows 2p,2p+1), 12 floats (48 B, 16B-aligned):
//     [0..3]  x0 x1 y0 y1          (x,y = 20*p)
//     [4..7]  z0 z1 -w0 -w1        (w = log2e*|20p|^2, stored negated)
//     [8..9] -f0 -f1  [10..11] pad (f = log2e*|fea2|^2, stored negated)
//   -> the pair kernel's pk-epilogue reads 2xb128+1xb64 per 2 pairs and the
//      v2f halves come out pre-paired (zero packing moves).
// ---------------------------------------------------------------------------
__global__ __launch_bounds__(BLKP) void precompute_kernel(
    const float* __restrict__ points,
    const float* __restrict__ fea1,
    const float* __restrict__ fea2,
    float4* __restrict__ xp,
    float* __restrict__ f1n,
    float* __restrict__ jpk,
    short* __restrict__ f2hi,
    short* __restrict__ f2lo,
    float* __restrict__ acc,
    float* __restrict__ out,
    int BN, int Bsz)
{
    int r = blockIdx.x * BLKP + threadIdx.x;
    if (r < Bsz) out[r] = 0.0f;
    if (r >= BN) return;
#pragma unroll
    for (int s = 0; s < 5; ++s) acc[s * BN + r] = 0.0f;

    const float s20 = 20.0f;                 // 1/SIGMA
    float x = points[3*r+0] * s20;
    float y = points[3*r+1] * s20;
    float z = points[3*r+2] * s20;
    float4 v; v.x = x; v.y = y; v.z = z;
    v.w = (x*x + y*y + z*z) * LOG2E;
    xp[r] = v;

    // f1 norm
    const float4* p1 = (const float4*)(fea1 + (size_t)r * D);
    float n1 = 0.f;
#pragma unroll
    for (int k = 0; k < D/4; ++k) {
        float4 a = p1[k];
        n1 = fmaf(a.x,a.x, fmaf(a.y,a.y, fmaf(a.z,a.z, fmaf(a.w,a.w, n1))));
    }
    f1n[r] = n1 * LOG2E;

    // f2: norm + hi/lo split, scattered fragment-major
    const int t = r >> 4;                    // global 16-row tile id
    const int m = r & 15;
    const float* p2 = fea2 + (size_t)r * D;
    float n2 = 0.f;
#pragma unroll
    for (int q = 0; q < 4; ++q) {
        float4 v0 = *(const float4*)(p2 + q*8);
        float4 v1 = *(const float4*)(p2 + q*8 + 4);
        float e[8] = {v0.x,v0.y,v0.z,v0.w,v1.x,v1.y,v1.z,v1.w};
        short8 h, l;
#pragma unroll
        for (int k = 0; k < 8; ++k) {
            n2 = fmaf(e[k], e[k], n2);
            short hh = f2bf(e[k]);
            h[k] = hh;
            l[k] = f2bf(e[k] - bf2f(hh));
        }
        size_t off = ((size_t)t * 64 + m + 16*q) * 8;
        *(short8*)&f2hi[off] = h;
        *(short8*)&f2lo[off] = l;
    }

    // paired-SoA j-scalar pack
    float* jb = jpk + (size_t)(r >> 1) * 12 + (r & 1);
    jb[0] = v.x;
    jb[2] = v.y;
    jb[4] = v.z;
    jb[6] = -v.w;
    jb[8] = -n2 * LOG2E;
}

// ---------------------------------------------------------------------------
// Kernel A: pair loop -- R4 structure with a PACKED (v_pk_f32) epilogue.
//   Per 16x16 tile each lane handles 4 pairs (rows r=0..3, one i-col).
//   c[2h],c[2h+1] are adjacent MFMA result regs -> natural v2f pairs; the
//   j-scalars arrive pre-paired from sJP (2xb128+1xb64 per 2 pairs).
//   Arithmetic per pair is bit-identical to the 84.4us R4 kernel (same fma
//   order; x-y replaced by x+(-y) with negated stores); only the 4-term
//   accumulation association differs ((r0+r2)+(r1+r3)).
//   Model: VALU 53K->~30K cy/CU (~13us), LDS 52K->~46K (~19us).
// ---------------------------------------------------------------------------
__global__ __launch_bounds__(BLK, 8) void pair_kernel(
    const float* __restrict__ fea1,
    const short* __restrict__ f2hi,
    const short* __restrict__ f2lo,
    const float* __restrict__ jpk,
    const float4* __restrict__ xp,
    const float* __restrict__ f1n,
    float* __restrict__ acc,
    int N, int BN)
{
    __shared__ __align__(16) short sHi[SJ * D];   // 8 KB, fragment-major
    __shared__ __align__(16) short sLo[SJ * D];   // 8 KB
    __shared__ __align__(16) float sJP[(SJ/2) * 12]; // 3 KB paired j-scalars

    const int tid  = threadIdx.x;
    const int lane = tid & 63;
    const int wv   = tid >> 6;
    const int m    = lane & 15;        // i-offset (B n-index / C col)
    const int q    = lane >> 4;        // k-octet / j-quad

    const int ibpb  = N / 64;          // i-blocks per batch
    const int b     = blockIdx.x / ibpb;
    const int ibase = blockIdx.x * 64 + wv * 16;
    const int JCH   = N / NCH;
    const int jc0   = blockIdx.y * JCH;

    // ---- B fragments: f1 rows of this wave's 16 i's, split hi/lo ----
    const float* f1p = fea1 + (size_t)(ibase + m) * D + q * 8;
    float4 bv0 = *(const float4*)(f1p);
    float4 bv1 = *(const float4*)(f1p + 4);
    float bf[8] = {bv0.x,bv0.y,bv0.z,bv0.w,bv1.x,bv1.y,bv1.z,bv1.w};
    short8 Bhi, Blo;
#pragma unroll
    for (int k = 0; k < 8; ++k) {
        short h = f2bf(bf[k]);
        Bhi[k] = h;
        Blo[k] = f2bf(bf[k] - bf2f(h));
    }

    const float L2 = 2.0f * LOG2E;
    float4 xi = xp[ibase + m];
    float nfi = -f1n[ibase + m];       // -log2e*|f1_i|^2
    v2f vxx2 = {xi.x * L2, xi.x * L2};
    v2f vxy2 = {xi.y * L2, xi.y * L2};
    v2f vxz2 = {xi.z * L2, xi.z * L2};
    v2f vmw2 = {-xi.w, -xi.w};
    v2f vnf2 = {nfi, nfi};
    v2f vL2  = {L2, L2};

    // accumulators (x-half: even r; y-half: odd r)
    v2f sA2  = {0.f, 0.f};
    v2f sB2  = {0.f, 0.f};
    v2f s2a2 = {0.f, 0.f};
    v2f s2b2 = {0.f, 0.f};
    v2f sab2 = {0.f, 0.f};

    const short* gHi = f2hi + ((size_t)(b * N + jc0) >> 4) * 512;
    const short* gLo = f2lo + ((size_t)(b * N + jc0) >> 4) * 512;
    const float* gJP = jpk  + ((size_t)(b * N + jc0) >> 1) * 12;

    for (int s = 0; s < JCH; s += SJ) {
        // ---- stage: pure contiguous copies ----
        const uint4* srcH = (const uint4*)(gHi + (size_t)(s >> 4) * 512);
        const uint4* srcL = (const uint4*)(gLo + (size_t)(s >> 4) * 512);
        const uint4* srcJ = (const uint4*)(gJP + (size_t)(s >> 1) * 12);
        uint4* dstH = (uint4*)sHi;
        uint4* dstL = (uint4*)sLo;
        dstH[tid]       = srcH[tid];
        dstH[tid + 256] = srcH[tid + 256];
        dstL[tid]       = srcL[tid];
        dstL[tid + 256] = srcL[tid + 256];
        if (tid < (SJ/2) * 12 * 4 / 16)              // 192 uint4 = 3 KB
            ((uint4*)sJP)[tid] = srcJ[tid];
        __syncthreads();

        // ---- compute: 8 16x16 pair tiles ----
#pragma unroll 2
        for (int jt8 = 0; jt8 < SJ/16; ++jt8) {
            const short8 Ahi = *(const short8*)&sHi[(jt8 * 64 + lane) * 8];
            const short8 Alo = *(const short8*)&sLo[(jt8 * 64 + lane) * 8];
            floatx4 c = {0.f, 0.f, 0.f, 0.f};
            c = __builtin_amdgcn_mfma_f32_16x16x32_bf16(Ahi, Bhi, c, 0, 0, 0);
            c = __builtin_amdgcn_mfma_f32_16x16x32_bf16(Ahi, Blo, c, 0, 0, 0);
            c = __builtin_amdgcn_mfma_f32_16x16x32_bf16(Alo, Bhi, c, 0, 0, 0);
#pragma unroll
            for (int h = 0; h < 2; ++h) {
                const int jp = jt8 * 8 + q * 2 + h;   // pair idx (j=2jp,2jp+1)
                float4 XY = *(const float4*)&sJP[jp * 12 + 0];
                float4 ZW = *(const float4*)&sJP[jp * 12 + 4];
                v2f    Fn = *(const v2f*)  &sJP[jp * 12 + 8];
                v2f xx = {XY.x, XY.y};
                v2f yy = {XY.z, XY.w};
                v2f zz = {ZW.x, ZW.y};
                v2f wn = {ZW.z, ZW.w};                // -xj.w (pre-negated)
                v2f c2 = {c[2*h], c[2*h + 1]};
                v2f t0 = __builtin_elementwise_fma(xx, vxx2, vmw2);
                t0 = __builtin_elementwise_fma(yy, vxy2, t0);
                t0 = __builtin_elementwise_fma(zz, vxz2, t0);
                v2f aL = t0 + wn;                               // log2 spatial
                v2f bL = __builtin_elementwise_fma(c2, vL2, vnf2 + Fn); // log2 feat
                v2f ea = {fast_exp2(aL.x), fast_exp2(aL.y)};
                v2f eb = {fast_exp2(bL.x), fast_exp2(bL.y)};
                sA2 += ea;
                sB2 += eb;
                s2a2 = __builtin_elementwise_fma(ea, ea, s2a2);
                s2b2 = __builtin_elementwise_fma(eb, eb, s2b2);
                sab2 = __builtin_elementwise_fma(ea, eb, sab2);
            }
        }
        __syncthreads();
    }

    // fold the even/odd-r partial sums
    float vA  = sA2.x  + sA2.y;
    float vB  = sB2.x  + sB2.y;
    float v2a = s2a2.x + s2a2.y;
    float v2b = s2b2.x + s2b2.y;
    float vab = sab2.x + sab2.y;

    // ---- reduce the 4 j-quads (lanes sharing lane&15) ----
    vA  += __shfl_xor(vA, 16);  vA  += __shfl_xor(vA, 32);
    vB  += __shfl_xor(vB, 16);  vB  += __shfl_xor(vB, 32);
    v2a += __shfl_xor(v2a, 16); v2a += __shfl_xor(v2a, 32);
    v2b += __shfl_xor(v2b, 16); v2b += __shfl_xor(v2b, 32);
    vab += __shfl_xor(vab, 16); vab += __shfl_xor(vab, 32);

    if (lane < 16) {
        int row = ibase + lane;
        atomicAdd(&acc[0*BN + row], vA);
        atomicAdd(&acc[1*BN + row], v2a);
        atomicAdd(&acc[2*BN + row], vB);
        atomicAdd(&acc[3*BN + row], v2b);
        atomicAdd(&acc[4*BN + row], vab);
    }
}

// ---------------------------------------------------------------------------
// Kernel B: combine per-row sums, weight, reduce into out[b] (out zeroed by P).
//   out[b] = sum_i w_i * ( S2a/A^2 - 2*Sab/(A*B) + S2b/B^2 )
// ---------------------------------------------------------------------------
__global__ __launch_bounds__(BLK) void finalize_kernel(
    const float* __restrict__ acc,
    const float* __restrict__ weights,
    float* __restrict__ out,
    int N, int BN)
{
    int row = blockIdx.x * BLK + threadIdx.x;
    int b   = (blockIdx.x * BLK) / N;

    float A   = acc[0*BN + row];
    float S2a = acc[1*BN + row];
    float Bt  = acc[2*BN + row];
    float S2b = acc[3*BN + row];
    float Sab = acc[4*BN + row];
    float invA = 1.0f / A;
    float invB = 1.0f / Bt;
    float val  = S2a*invA*invA - 2.0f*Sab*invA*invB + S2b*invB*invB;
    float sum  = weights[row] * val;

    __shared__ float red[BLK/64];
    for (int off = 32; off > 0; off >>= 1)
        sum += __shfl_down(sum, off);
    if ((threadIdx.x & 63) == 0) red[threadIdx.x >> 6] = sum;
    __syncthreads();
    if (threadIdx.x == 0) {
        float s = 0.f;
#pragma unroll
        for (int w = 0; w < BLK/64; ++w) s += red[w];
        atomicAdd(&out[b], s);
    }
}

// ---------------------------------------------------------------------------
extern "C" void kernel_launch(void* const* d_in, const int* in_sizes, int n_in,
                              void* d_out, int out_size, void* d_ws, size_t ws_size,
                              hipStream_t stream) {
    const float* points  = (const float*)d_in[0];
    const float* fea1    = (const float*)d_in[1];
    const float* fea2    = (const float*)d_in[2];
    const float* weights = (const float*)d_in[3];
    float* out = (float*)d_out;

    int B  = out_size;          // 2
    int BN = in_sizes[3];       // B*N = 8192
    int N  = BN / B;            // 4096

    // workspace (bytes):
    //   acc  : 5*BN*4   @ 0
    //   xp   : 4*BN*4   @ 5*BN*4
    //   f1n  : BN*4     @ 9*BN*4
    //   jpk  : 6*BN*4   @ 10*BN*4   ((BN/2) pairs * 12 floats)
    //   f2hi : BN*D*2   @ 16*BN*4
    //   f2lo : BN*D*2
    float*  acc  = (float*)d_ws;
    float4* xp   = (float4*)((char*)d_ws + (size_t)5  * BN * 4);
    float*  f1n  = (float*)((char*)d_ws + (size_t)9  * BN * 4);
    float*  jpk  = (float*)((char*)d_ws + (size_t)10 * BN * 4);
    short*  f2hi = (short*)((char*)d_ws + (size_t)16 * BN * 4);
    short*  f2lo = f2hi + (size_t)BN * D;

    precompute_kernel<<<dim3((BN + BLKP - 1) / BLKP), dim3(BLKP), 0, stream>>>(
        points, fea1, fea2, xp, f1n, jpk, f2hi, f2lo, acc, out, BN, B);

    dim3 grid(BN / 64, NCH);    // 128 x 16 = 2048 blocks (8 blocks/CU)
    pair_kernel<<<grid, dim3(BLK), 0, stream>>>(
        fea1, f2hi, f2lo, jpk, xp, f1n, acc, N, BN);

    finalize_kernel<<<dim3(BN / BLK), dim3(BLK), 0, stream>>>(acc, weights, out, N, BN);
}